// Round 13
// baseline (353.986 us; speedup 1.0000x reference)
//
#include <hip/hip_runtime.h>
#include <hip/hip_bf16.h>

typedef __bf16 bf16x8 __attribute__((ext_vector_type(8)));
typedef float  f32x4  __attribute__((ext_vector_type(4)));

#define C_DIM   200
#define HW_DIM  1024
#define NT      13            // 13 row/col tiles of 16 (padded 208)
#define PADC    208
#define BK      64            // k-elems staged per iteration
#define NKC     16            // 1024 / 64
#define ROWB    128           // bytes per LDS tile row (64 bf16)
#define TILEB   (PADC*ROWB)   // 26624 B per buffer
#define SLAB    (PADC*HW_DIM) // bf16 elems per ws slab

// global_load_lds: LDS dest = wave-uniform base + lane*16 (linear);
// global source is per-lane (pre-swizzled so data lands swizzled).
#define GLD16(gp, lp) __builtin_amdgcn_global_load_lds(                      \
    (const __attribute__((address_space(1))) unsigned int*)(gp),             \
    (__attribute__((address_space(3))) unsigned int*)(lp), 16, 0, 0)

__global__ __launch_bounds__(832, 4)
void spectral_corr_kernel(const float* __restrict__ x,
                          const float* __restrict__ temp,
                          float* __restrict__ out,
                          __hip_bfloat16* __restrict__ ws)
{
  __shared__ __align__(16) char sA[2][TILEB];
  __shared__ float d_lds[PADC];
  __shared__ float rs_lds[PADC];

  const int tid = threadIdx.x;
  const int b   = blockIdx.x;
  const int w   = tid >> 6;     // wave id 0..12 -> row tile
  const int l   = tid & 63;
  const int g   = l >> 4;       // 0..3
  const int c   = l & 15;       // 0..15

  const float*    xb = x  + (size_t)b * (C_DIM * HW_DIM);
  __hip_bfloat16* wb = ws + (size_t)b * SLAB;

  // ================= phase 1: fp32 -> bf16 slab (block-private) ==========
  // rows 0..199 flat = 204800 elems; pad rows 200..207 left as poison
  // (finite denormal; all pad-dependent outputs are discarded).
  for (int base = tid*8; base < C_DIM*HW_DIM; base += 832*8){
    float4 a0 = *(const float4*)(xb + base);
    float4 a1 = *(const float4*)(xb + base + 4);
    bf16x8 v;
    v[0]=(__bf16)a0.x; v[1]=(__bf16)a0.y; v[2]=(__bf16)a0.z; v[3]=(__bf16)a0.w;
    v[4]=(__bf16)a1.x; v[5]=(__bf16)a1.y; v[6]=(__bf16)a1.z; v[7]=(__bf16)a1.w;
    *reinterpret_cast<bf16x8*>(wb + base) = v;
  }
  __syncthreads();   // slab visible to phase-2 DMA (same block only)

  const float et = expf(temp[0]);

  // ================= phase 2: Gram GEMM via global_load_lds ==============
  // Staging: wave w issues 2 DMA instrs (8 rows each) per tile.
  // lane l -> sub-row si = l>>3, source chunk sc = (l&7) ^ si  (involution;
  // row&7 == si because 8*i ≡ 0 mod 8), so data lands XOR-swizzled in LDS.
  const int si = l >> 3;
  const int sc = (l & 7) ^ si;
  const int i0 = 2*w, i1 = 2*w + 1;                 // row-groups [8i,8i+8)
  const __hip_bfloat16* gs0 = wb + (size_t)(8*i0 + si)*HW_DIM + sc*8;
  const __hip_bfloat16* gs1 = wb + (size_t)(8*i1 + si)*HW_DIM + sc*8;

  f32x4 acc[NT];
  #pragma unroll
  for (int j=0;j<NT;++j) acc[j] = (f32x4){0.f,0.f,0.f,0.f};

  // prologue: stage k-chunk 0 into buffer 0
  GLD16(gs0, &sA[0][i0*1024]);
  GLD16(gs1, &sA[0][i1*1024]);
  __syncthreads();

  // ds_read bases: row = j*16 + c  ->  row&7 = c&7 (j-invariant swizzle);
  // fj addr = bufbase + rb_s + j*2048 (immediate), fw = fj at j==w.
  const int swz = (c & 7) << 4;
  const int rb0 = c*ROWB + ((     g*16) ^ swz);     // s=0 (k 0..31)
  const int rb1 = c*ROWB + ((64 + g*16) ^ swz);     // s=1 (k 32..63)

  for (int kc = 0; kc < NKC; ++kc){
    const char* bufc = sA[kc & 1];
    if (kc+1 < NKC){                                // stage next tile (DMA)
      char* bufn = sA[(kc+1)&1];
      GLD16(gs0 + (kc+1)*BK, &bufn[i0*1024]);
      GLD16(gs1 + (kc+1)*BK, &bufn[i1*1024]);
    }
    #pragma unroll
    for (int s = 0; s < 2; ++s){
      const char* p = bufc + (s ? rb1 : rb0);
      bf16x8 fw = *reinterpret_cast<const bf16x8*>(p + w*2048);
      #pragma unroll
      for (int j = 0; j < NT; ++j){
        bf16x8 fj = *reinterpret_cast<const bf16x8*>(p + j*2048);
        acc[j] = __builtin_amdgcn_mfma_f32_16x16x32_bf16(fw, fj, acc[j], 0, 0, 0);
      }
    }
    __syncthreads();   // drains vmcnt (DMA) + lgkmcnt, swaps buffers
  }

  // ---- diagonal of (bf16) G -> d_lds  (makes dcov_ii exactly 0)
  // C/D layout: col = lane&15, row-in-tile = 4*(lane>>4) + i
  #pragma unroll
  for (int j=0;j<NT;++j){
    if (j == w){
      #pragma unroll
      for (int i=0;i<4;++i)
        if (c == g*4 + i) d_lds[j*16 + c] = acc[j][i];
    }
  }
  __syncthreads();

  // ---- dcov + per-row partial sums (over valid cols < 200)
  float dr[4];
  #pragma unroll
  for (int i=0;i<4;++i) dr[i] = d_lds[w*16 + g*4 + i];
  float rsum[4] = {0.f,0.f,0.f,0.f};
  #pragma unroll
  for (int j=0;j<NT;++j){
    const float dc = d_lds[j*16 + c];
    const bool cv  = (j*16 + c) < C_DIM;
    #pragma unroll
    for (int i=0;i<4;++i){
      float v = dr[i] + dc - 2.0f*acc[j][i];
      v = fmaxf(v, 0.0f);
      v = sqrtf(fmaf(et, v, 1e-5f));
      acc[j][i] = v;
      if (cv) rsum[i] += v;
    }
  }
  #pragma unroll
  for (int m=1;m<16;m<<=1){
    #pragma unroll
    for (int i=0;i<4;++i) rsum[i] += __shfl_xor(rsum[i], m, 64);
  }
  if (c == 0){
    #pragma unroll
    for (int i=0;i<4;++i) rs_lds[w*16 + g*4 + i] = rsum[i];
  }
  __syncthreads();

  float tot = 0.f;
  for (int r=0;r<C_DIM;++r) tot += rs_lds[r];
  const float inv  = 1.0f/(float)C_DIM;
  const float totm = tot*inv*inv;

  // ---- fused double-centering + store:  out = rm_r + rm_c - totm - dcov
  float* ob = out + b*(C_DIM*C_DIM);
  float rmr[4];
  #pragma unroll
  for (int i=0;i<4;++i) rmr[i] = rs_lds[w*16 + g*4 + i]*inv;
  #pragma unroll
  for (int j=0;j<NT;++j){
    const int col = j*16 + c;
    if (col < C_DIM){
      const float rmc = rs_lds[col]*inv;
      #pragma unroll
      for (int i=0;i<4;++i){
        const int row = w*16 + g*4 + i;
        if (row < C_DIM)
          ob[row*C_DIM + col] = rmr[i] + rmc - totm - acc[j][i];
      }
    }
  }
}

extern "C" void kernel_launch(void* const* d_in, const int* in_sizes, int n_in,
                              void* d_out, int out_size, void* d_ws, size_t ws_size,
                              hipStream_t stream) {
  const float* x    = (const float*)d_in[0];
  const float* temp = (const float*)d_in[1];
  float* out        = (float*)d_out;
  __hip_bfloat16* ws = (__hip_bfloat16*)d_ws;
  spectral_corr_kernel<<<dim3(256), dim3(832), 0, stream>>>(x, temp, out, ws);
}

// Round 14
// 341.607 us; speedup vs baseline: 1.0362x; 1.0362x over previous
//
#include <hip/hip_runtime.h>
#include <hip/hip_bf16.h>

typedef __bf16 bf16x8 __attribute__((ext_vector_type(8)));
typedef float  f32x4  __attribute__((ext_vector_type(4)));

#define C_DIM   200
#define HW_DIM  1024
#define NT      13            // 13 row/col tiles of 16 (padded 208)
#define PADC    208
#define BK      64            // k-elems staged per iteration
#define NKC     16            // 1024 / 64
#define ROWB    128           // bytes per LDS tile row (64 bf16)
#define TILEB   (PADC*ROWB)   // 26624 B per buffer
#define SLAB    (PADC*HW_DIM) // bf16 elems per ws slab

// global_load_lds: LDS dest = wave-uniform base + lane*16 (linear);
// global source is per-lane (pre-swizzled so data lands swizzled).
#define GLD16(gp, lp) __builtin_amdgcn_global_load_lds(                      \
    (const __attribute__((address_space(1))) unsigned int*)(gp),             \
    (__attribute__((address_space(3))) unsigned int*)(lp), 16, 0, 0)

__device__ __forceinline__ bf16x8 pack8(float4 a, float4 b){
  bf16x8 v;
  v[0]=(__bf16)a.x; v[1]=(__bf16)a.y; v[2]=(__bf16)a.z; v[3]=(__bf16)a.w;
  v[4]=(__bf16)b.x; v[5]=(__bf16)b.y; v[6]=(__bf16)b.z; v[7]=(__bf16)b.w;
  return v;
}

__global__ __launch_bounds__(832, 4)
void spectral_corr_kernel(const float* __restrict__ x,
                          const float* __restrict__ temp,
                          float* __restrict__ out,
                          __hip_bfloat16* __restrict__ ws)
{
  __shared__ __align__(16) char sA[2][TILEB];
  __shared__ float d_lds[PADC];
  __shared__ float rs_lds[PADC];

  const int tid = threadIdx.x;
  const int b   = blockIdx.x;
  const int w   = tid >> 6;     // wave id 0..12 -> row tile
  const int l   = tid & 63;
  const int g   = l >> 4;       // 0..3
  const int c   = l & 15;       // 0..15

  const float*    xb = x  + (size_t)b * (C_DIM * HW_DIM);
  __hip_bfloat16* wb = ws + (size_t)b * SLAB;

  // ---- conversion slot mapping: per chunk, 200 rows x 8 sub-chunks of
  //      8 elems = 1600 slots; thread t handles slots t and t+832.
  const int r_a  = tid >> 3,        c8_a = tid & 7;          // rows 0..103
  const int s_b  = tid + 832;
  const int r_b  = s_b >> 3,        c8_b = s_b & 7;          // rows 104..199(+)
  const bool vb  = (s_b < 1600);

  // ---- DMA staging (unchanged from round 13): wave w stages row-groups
  //      i0,i1; lane l -> sub-row si, pre-swizzled source chunk sc.
  const int si = l >> 3;
  const int sc = (l & 7) ^ si;
  const int i0 = 2*w, i1 = 2*w + 1;
  const __hip_bfloat16* gs0 = wb + (size_t)(8*i0 + si)*HW_DIM + sc*8;
  const __hip_bfloat16* gs1 = wb + (size_t)(8*i1 + si)*HW_DIM + sc*8;

  f32x4 acc[NT];
  #pragma unroll
  for (int j=0;j<NT;++j) acc[j] = (f32x4){0.f,0.f,0.f,0.f};

  // ================= prologue: convert chunks 0,1 -> slab =================
  #pragma unroll
  for (int cc = 0; cc < 2; ++cc){
    {
      const float* p = xb + (size_t)r_a*HW_DIM + cc*BK + c8_a*8;
      float4 f0 = *(const float4*)p, f1 = *(const float4*)(p+4);
      *reinterpret_cast<bf16x8*>(wb + (size_t)r_a*HW_DIM + cc*BK + c8_a*8) = pack8(f0,f1);
    }
    if (vb){
      const float* p = xb + (size_t)r_b*HW_DIM + cc*BK + c8_b*8;
      float4 f0 = *(const float4*)p, f1 = *(const float4*)(p+4);
      *reinterpret_cast<bf16x8*>(wb + (size_t)r_b*HW_DIM + cc*BK + c8_b*8) = pack8(f0,f1);
    }
  }
  __syncthreads();               // slab chunks 0,1 drained & visible

  GLD16(gs0, &sA[0][i0*1024]);   // DMA chunk 0 -> buf0
  GLD16(gs1, &sA[0][i1*1024]);
  __syncthreads();               // buf0 ready

  const float et = expf(temp[0]);

  const int swz = (c & 7) << 4;
  const int rb0 = c*ROWB + ((     g*16) ^ swz);   // s=0 (k 0..31)
  const int rb1 = c*ROWB + ((64 + g*16) ^ swz);   // s=1 (k 32..63)

  // ================= fused 3-stage pipeline ===============================
  // iter kc: DMA c(kc+1) | x-load c(kc+2) | compute c(kc) | store c(kc+2)
  for (int kc = 0; kc < NKC; ++kc){
    const char* bufc = sA[kc & 1];
    if (kc+1 < NKC){                              // stage next tile (DMA)
      char* bufn = sA[(kc+1)&1];
      GLD16(gs0 + (kc+1)*BK, &bufn[i0*1024]);
      GLD16(gs1 + (kc+1)*BK, &bufn[i1*1024]);
    }
    float4 fa0, fa1, fb0, fb1;
    const bool cv = (kc+2 < NKC);
    if (cv){                                      // issue x loads EARLY
      const float* pa = xb + (size_t)r_a*HW_DIM + (kc+2)*BK + c8_a*8;
      fa0 = *(const float4*)pa; fa1 = *(const float4*)(pa+4);
      if (vb){
        const float* pb = xb + (size_t)r_b*HW_DIM + (kc+2)*BK + c8_b*8;
        fb0 = *(const float4*)pb; fb1 = *(const float4*)(pb+4);
      }
    }
    #pragma unroll
    for (int s = 0; s < 2; ++s){                  // compute chunk kc
      const char* p = bufc + (s ? rb1 : rb0);
      bf16x8 fw = *reinterpret_cast<const bf16x8*>(p + w*2048);
      #pragma unroll
      for (int j = 0; j < NT; ++j){
        bf16x8 fj = *reinterpret_cast<const bf16x8*>(p + j*2048);
        acc[j] = __builtin_amdgcn_mfma_f32_16x16x32_bf16(fw, fj, acc[j], 0, 0, 0);
      }
    }
    if (cv){                                      // pack+store LATE
      *reinterpret_cast<bf16x8*>(wb + (size_t)r_a*HW_DIM + (kc+2)*BK + c8_a*8) = pack8(fa0,fa1);
      if (vb)
        *reinterpret_cast<bf16x8*>(wb + (size_t)r_b*HW_DIM + (kc+2)*BK + c8_b*8) = pack8(fb0,fb1);
    }
    __syncthreads();   // drains DMA c(kc+1) + stores c(kc+2); swap buffers
  }

  // ---- diagonal of (bf16) G -> d_lds  (makes dcov_ii exactly 0)
  // C/D layout: col = lane&15, row-in-tile = 4*(lane>>4) + i
  #pragma unroll
  for (int j=0;j<NT;++j){
    if (j == w){
      #pragma unroll
      for (int i=0;i<4;++i)
        if (c == g*4 + i) d_lds[j*16 + c] = acc[j][i];
    }
  }
  __syncthreads();

  // ---- dcov + per-row partial sums (over valid cols < 200)
  float dr[4];
  #pragma unroll
  for (int i=0;i<4;++i) dr[i] = d_lds[w*16 + g*4 + i];
  float rsum[4] = {0.f,0.f,0.f,0.f};
  #pragma unroll
  for (int j=0;j<NT;++j){
    const float dc = d_lds[j*16 + c];
    const bool cvv = (j*16 + c) < C_DIM;
    #pragma unroll
    for (int i=0;i<4;++i){
      float v = dr[i] + dc - 2.0f*acc[j][i];
      v = fmaxf(v, 0.0f);
      v = sqrtf(fmaf(et, v, 1e-5f));
      acc[j][i] = v;
      if (cvv) rsum[i] += v;
    }
  }
  #pragma unroll
  for (int m=1;m<16;m<<=1){
    #pragma unroll
    for (int i=0;i<4;++i) rsum[i] += __shfl_xor(rsum[i], m, 64);
  }
  if (c == 0){
    #pragma unroll
    for (int i=0;i<4;++i) rs_lds[w*16 + g*4 + i] = rsum[i];
  }
  __syncthreads();

  float tot = 0.f;
  for (int r=0;r<C_DIM;++r) tot += rs_lds[r];
  const float inv  = 1.0f/(float)C_DIM;
  const float totm = tot*inv*inv;

  // ---- fused double-centering + store:  out = rm_r + rm_c - totm - dcov
  float* ob = out + b*(C_DIM*C_DIM);
  float rmr[4];
  #pragma unroll
  for (int i=0;i<4;++i) rmr[i] = rs_lds[w*16 + g*4 + i]*inv;
  #pragma unroll
  for (int j=0;j<NT;++j){
    const int col = j*16 + c;
    if (col < C_DIM){
      const float rmc = rs_lds[col]*inv;
      #pragma unroll
      for (int i=0;i<4;++i){
        const int row = w*16 + g*4 + i;
        if (row < C_DIM)
          ob[row*C_DIM + col] = rmr[i] + rmc - totm - acc[j][i];
      }
    }
  }
}

extern "C" void kernel_launch(void* const* d_in, const int* in_sizes, int n_in,
                              void* d_out, int out_size, void* d_ws, size_t ws_size,
                              hipStream_t stream) {
  const float* x    = (const float*)d_in[0];
  const float* temp = (const float*)d_in[1];
  float* out        = (float*)d_out;
  __hip_bfloat16* ws = (__hip_bfloat16*)d_ws;
  spectral_corr_kernel<<<dim3(256), dim3(832), 0, stream>>>(x, temp, out, ws);
}